// Round 8
// baseline (336.338 us; speedup 1.0000x reference)
//
#include <hip/hip_runtime.h>
#include <hip/hip_bf16.h>

typedef __bf16 bf16_t;
typedef bf16_t bf16x4 __attribute__((ext_vector_type(4)));
typedef bf16_t bf16x8 __attribute__((ext_vector_type(8)));
typedef float f32x4 __attribute__((ext_vector_type(4)));
typedef unsigned int u32;

#define MFMA16(a, b, c) __builtin_amdgcn_mfma_f32_16x16x32_bf16((a), (b), (c), 0, 0, 0)

// element-index XOR swizzles (bf16 elems): XOR bits 3..5 keyed by row&7
__device__ __forceinline__ int sxi(int row, int e) { return row * 256 + (e ^ ((row & 7) << 3)); }
__device__ __forceinline__ int ski(int row, int e) { return row * 64 + (e ^ ((row & 7) << 3)); }

__device__ __forceinline__ u32 pk2(float a, float b) {
  union { bf16_t h[2]; u32 u; } x;
  x.h[0] = (bf16_t)a; x.h[1] = (bf16_t)b;
  return x.u;
}

// ---------------------------------------------------------------------------
// prep kernels
// ---------------------------------------------------------------------------
__global__ void transpose_to_bf16(const float* __restrict__ in, bf16_t* __restrict__ outp,
                                  int K, int N) {
  __shared__ float tile[32][33];
  const int k0 = blockIdx.x * 32;
  const int n0 = blockIdx.y * 32;
  const int tx = threadIdx.x;
  const int ty = threadIdx.y;
#pragma unroll
  for (int i = 0; i < 32; i += 8)
    tile[ty + i][tx] = in[(size_t)(k0 + ty + i) * N + (n0 + tx)];
  __syncthreads();
#pragma unroll
  for (int i = 0; i < 32; i += 8)
    outp[(size_t)(n0 + ty + i) * K + (k0 + tx)] = (bf16_t)tile[tx][ty + i];
}

__global__ void rope_table(const float* __restrict__ invf, float2* __restrict__ cs) {
  const int idx = blockIdx.x * 256 + threadIdx.x;  // 0..2047 = 64*32
  const int t = idx >> 5;
  const int i = idx & 31;
  const float f = (float)t * invf[i];
  cs[idx] = make_float2(cosf(f), sinf(f));
}

// ---------------------------------------------------------------------------
// fused temporal-axial attention
// grid: 2048 = (b, hh*32+ww); block: 512 threads = 8 waves.
// wave (h = wid>>1, hf = wid&1): head h, row-half hf (t-half for Q/O, s-half
// for K/V). Per-wave accumulators are 32 f32 -> fits 128-VGPR cap at 2 blk/CU.
// LDS: A 32KB (x-tile -> V^T per head) + B 32KB (K -> P -> O) = 64KB.
// ---------------------------------------------------------------------------
__global__ __launch_bounds__(512, 4) void taa_fused(
    const float* __restrict__ x, const bf16_t* __restrict__ wqkvT,
    const bf16_t* __restrict__ woutT, const float* __restrict__ bout,
    const float2* __restrict__ ropecs, float* __restrict__ out) {
  __shared__ __attribute__((aligned(16))) bf16_t sA[64 * 256];  // x -> V^T[h][d][s]
  __shared__ __attribute__((aligned(16))) bf16_t sB[64 * 256];  // K[h][s][dd] -> P[h][t][s] -> O[t][256]

  const int tid = threadIdx.x;
  const int wid = tid >> 6;   // 0..7
  const int h = wid >> 1;     // head
  const int hf = wid & 1;     // row-half
  const int l = tid & 63;
  const int l16 = l & 15;
  const int g = l >> 4;  // 0..3

  const int site = blockIdx.x;
  const int b = site >> 10;
  const int sp = site & 1023;

  const size_t TS = 1024 * 256;  // time stride in elements
  const float* xp = x + (size_t)((b * 64) * 1024 + sp) * 256;
  float* op = out + (size_t)((b * 64) * 1024 + sp) * 256;

  // ---- P1: x tile (64x256 f32) -> sA bf16 (swizzled) ----
#pragma unroll
  for (int it = 0; it < 8; ++it) {
    const int idx = tid + it * 512;
    const int t = idx >> 6;
    const int c = (idx & 63) * 4;
    const float4 v = *(const float4*)(xp + (size_t)t * TS + c);
    bf16x4 o4;
    o4[0] = (bf16_t)v.x; o4[1] = (bf16_t)v.y; o4[2] = (bf16_t)v.z; o4[3] = (bf16_t)v.w;
    *(bf16x4*)&sA[sxi(t, c)] = o4;
  }
  __syncthreads();  // B1

  // ---- P2a: Q^T = WqT @ x^T (rows dd 0..63, cols t = wave's half), rope -> qtb ----
  u32 qtb[4][2][2];
  {
    f32x4 qt[4][2] = {};
#pragma unroll
    for (int k0 = 0; k0 < 256; k0 += 32) {
      const int ko = k0 + 8 * g;
      bf16x8 aw[4], bx[2];
#pragma unroll
      for (int m = 0; m < 4; ++m)
        aw[m] = *(const bf16x8*)&wqkvT[(size_t)(h * 64 + 16 * m + l16) * 256 + ko];
#pragma unroll
      for (int n = 0; n < 2; ++n) bx[n] = *(const bf16x8*)&sA[sxi(hf * 32 + 16 * n + l16, ko)];
#pragma unroll
      for (int m = 0; m < 4; ++m)
#pragma unroll
        for (int n = 0; n < 2; ++n) qt[m][n] = MFMA16(aw[m], bx[n], qt[m][n]);
    }
    const float qs = 0.125f * 1.44269504088896f;
#pragma unroll
    for (int m = 0; m < 4; ++m)
#pragma unroll
      for (int n = 0; n < 2; ++n)
#pragma unroll
        for (int c = 0; c < 2; ++c) {
          const float v0 = qt[m][n][2 * c], v1 = qt[m][n][2 * c + 1];
          const int tg = hf * 32 + 16 * n + l16;
          const float2 cs = ropecs[tg * 32 + 8 * m + 2 * g + c];
          qtb[m][n][c] = pk2((v0 * cs.x - v1 * cs.y) * qs, (v1 * cs.x + v0 * cs.y) * qs);
        }
  }

  // ---- P2b: K = x @ Wk (rows s = wave's half), rope, -> sB immediately (ka dies) ----
  {
    f32x4 ka[2][4] = {};
#pragma unroll
    for (int k0 = 0; k0 < 256; k0 += 32) {
      const int ko = k0 + 8 * g;
      bf16x8 ax[2];
#pragma unroll
      for (int m = 0; m < 2; ++m) ax[m] = *(const bf16x8*)&sA[sxi(hf * 32 + 16 * m + l16, ko)];
#pragma unroll
      for (int n = 0; n < 4; ++n) {
        const bf16x8 bw = *(const bf16x8*)&wqkvT[(size_t)(256 + h * 64 + 16 * n + l16) * 256 + ko];
#pragma unroll
        for (int m = 0; m < 2; ++m) ka[m][n] = MFMA16(ax[m], bw, ka[m][n]);
      }
    }
#pragma unroll
    for (int m = 0; m < 2; ++m)
#pragma unroll
      for (int n = 0; n < 4; ++n)
#pragma unroll
        for (int r = 0; r < 4; ++r) {
          const float v = ka[m][n][r];
          const float p = __shfl_xor(v, 1);
          const int s = hf * 32 + 16 * m + 4 * g + r;
          const int dd = 16 * n + l16;
          const float2 cs = ropecs[s * 32 + 8 * n + (l16 >> 1)];
          const float o = (dd & 1) ? (v * cs.x + p * cs.y) : (v * cs.x - p * cs.y);
          sB[h * 4096 + ski(s, dd)] = (bf16_t)o;  // K region: no aliasing, write now
        }
  }

  // ---- P2c: V = x @ Wv (rows s = wave's half); va held until B2 ----
  f32x4 va[2][4] = {};
#pragma unroll
  for (int k0 = 0; k0 < 256; k0 += 32) {
    const int ko = k0 + 8 * g;
    bf16x8 ax[2];
#pragma unroll
    for (int m = 0; m < 2; ++m) ax[m] = *(const bf16x8*)&sA[sxi(hf * 32 + 16 * m + l16, ko)];
#pragma unroll
    for (int n = 0; n < 4; ++n) {
      const bf16x8 bw = *(const bf16x8*)&wqkvT[(size_t)(512 + h * 64 + 16 * n + l16) * 256 + ko];
#pragma unroll
      for (int m = 0; m < 2; ++m) va[m][n] = MFMA16(ax[m], bw, va[m][n]);
    }
  }
  __syncthreads();  // B2: x dead everywhere

  // V^T[h][d][s] into sA (transposed scatter)
#pragma unroll
  for (int m = 0; m < 2; ++m)
#pragma unroll
    for (int n = 0; n < 4; ++n)
#pragma unroll
      for (int r = 0; r < 4; ++r)
        sA[h * 4096 + ski(16 * n + l16, hf * 32 + 16 * m + 4 * g + r)] = (bf16_t)va[m][n][r];
  __syncthreads();  // B3: K, V^T visible

  // ---- 3a: S^T = K @ Q^T (A = K full 64 rows from sB; B = Q^T via pair-shfl) ----
  f32x4 sc[4][2] = {};
#pragma unroll
  for (int ks = 0; ks < 2; ++ks) {
    const int ko = ks * 32 + 8 * g;
    bf16x8 ak[4];
#pragma unroll
    for (int m = 0; m < 4; ++m) ak[m] = *(const bf16x8*)&sB[h * 4096 + ski(16 * m + l16, ko)];
#pragma unroll
    for (int n = 0; n < 2; ++n) {
      union { u32 u[4]; bf16x8 v; } uu;
#pragma unroll
      for (int k2 = 0; k2 < 4; ++k2) {
        const int src = ((((2 * g + (k2 >> 1)) & 3) << 4) | l16);
        const u32 a0 = (u32)__shfl((int)qtb[2 * ks][n][k2 & 1], src);
        const u32 a1 = (u32)__shfl((int)qtb[2 * ks + 1][n][k2 & 1], src);
        uu.u[k2] = (g & 2) ? a1 : a0;
      }
#pragma unroll
      for (int m = 0; m < 4; ++m) sc[m][n] = MFMA16(ak[m], uu.v, sc[m][n]);
    }
  }
  __syncthreads();  // B4: all K reads done -> P may overwrite

  // ---- 3b: causal softmax over s; P[t][s] -> sB (over K) ----
#pragma unroll
  for (int n = 0; n < 2; ++n) {
    const int t = hf * 32 + 16 * n + l16;
    float vals[16];
    float mx = -3.0e38f;
#pragma unroll
    for (int m = 0; m < 4; ++m)
#pragma unroll
      for (int r = 0; r < 4; ++r) {
        const int s = 16 * m + 4 * g + r;
        const float v = (s <= t) ? sc[m][n][r] : -3.0e38f;
        vals[4 * m + r] = v;
        mx = fmaxf(mx, v);
      }
    mx = fmaxf(mx, __shfl_xor(mx, 16));
    mx = fmaxf(mx, __shfl_xor(mx, 32));
    float sum = 0.f;
#pragma unroll
    for (int i = 0; i < 16; ++i) {
      vals[i] = exp2f(vals[i] - mx);
      sum += vals[i];
    }
    sum += __shfl_xor(sum, 16);
    sum += __shfl_xor(sum, 32);
    const float inv = 1.0f / sum;
#pragma unroll
    for (int m = 0; m < 4; ++m) {
      bf16x4 p4;
#pragma unroll
      for (int r = 0; r < 4; ++r) p4[r] = (bf16_t)(vals[4 * m + r] * inv);
      *(bf16x4*)&sB[h * 4096 + ski(t, 16 * m + 4 * g)] = p4;
    }
  }

  // ---- 3c: O = P @ V (A = own P rows; B = V^T rows d, b128) ----
  f32x4 oacc[2][4] = {};
#pragma unroll
  for (int ks = 0; ks < 2; ++ks) {
    const int ko = ks * 32 + 8 * g;
    bf16x8 ap[2], bv[4];
#pragma unroll
    for (int m = 0; m < 2; ++m)
      ap[m] = *(const bf16x8*)&sB[h * 4096 + ski(hf * 32 + 16 * m + l16, ko)];
#pragma unroll
    for (int n = 0; n < 4; ++n)
      bv[n] = *(const bf16x8*)&sA[h * 4096 + ski(16 * n + l16, ko)];
#pragma unroll
    for (int m = 0; m < 2; ++m)
#pragma unroll
      for (int n = 0; n < 4; ++n) oacc[m][n] = MFMA16(ap[m], bv[n], oacc[m][n]);
  }
  __syncthreads();  // B5: P/V dead -> O may overwrite sB

  // ---- P4: O -> sB[t][h*64+d] (full 64x256, sxi) ----
#pragma unroll
  for (int m = 0; m < 2; ++m)
#pragma unroll
    for (int n = 0; n < 4; ++n)
#pragma unroll
      for (int r = 0; r < 4; ++r)
        sB[sxi(hf * 32 + 16 * m + 4 * g + r, h * 64 + 16 * n + l16)] = (bf16_t)oacc[m][n][r];
  __syncthreads();  // B6

  // ---- P5: out = O @ w_out + b (wave -> 32 cols: wid*32..) ----
  f32x4 acc[4][2] = {};
#pragma unroll
  for (int k0 = 0; k0 < 256; k0 += 32) {
    const int ko = k0 + 8 * g;
    bf16x8 af[4];
#pragma unroll
    for (int m = 0; m < 4; ++m) af[m] = *(const bf16x8*)&sB[sxi(16 * m + l16, ko)];
#pragma unroll
    for (int n = 0; n < 2; ++n) {
      const bf16x8 bw = *(const bf16x8*)&woutT[(size_t)(wid * 32 + 16 * n + l16) * 256 + ko];
#pragma unroll
      for (int m = 0; m < 4; ++m) acc[m][n] = MFMA16(af[m], bw, acc[m][n]);
    }
  }
  float bb[2];
#pragma unroll
  for (int n = 0; n < 2; ++n) bb[n] = bout[wid * 32 + 16 * n + l16];
#pragma unroll
  for (int m = 0; m < 4; ++m)
#pragma unroll
    for (int n = 0; n < 2; ++n)
#pragma unroll
      for (int r = 0; r < 4; ++r) {
        const int t = 16 * m + 4 * g + r;
        const int col = wid * 32 + 16 * n + l16;
        op[(size_t)t * TS + col] = acc[m][n][r] + bb[n];
      }
}

// ---------------------------------------------------------------------------
extern "C" void kernel_launch(void* const* d_in, const int* in_sizes, int n_in,
                              void* d_out, int out_size, void* d_ws, size_t ws_size,
                              hipStream_t stream) {
  const float* x = (const float*)d_in[0];
  const float* wqkv = (const float*)d_in[1];
  const float* wout = (const float*)d_in[2];
  const float* bout = (const float*)d_in[3];
  const float* invf = (const float*)d_in[4];
  float* out = (float*)d_out;

  char* ws = (char*)d_ws;
  bf16_t* wqkvT = (bf16_t*)ws;                       // 768*256*2 = 393216 B
  bf16_t* woutT = (bf16_t*)(ws + 393216);            // 256*256*2 = 131072 B
  float2* ropecs = (float2*)(ws + 393216 + 131072);  // 2048*8 = 16384 B

  transpose_to_bf16<<<dim3(8, 24), dim3(32, 8), 0, stream>>>(wqkv, wqkvT, 256, 768);
  transpose_to_bf16<<<dim3(8, 8), dim3(32, 8), 0, stream>>>(wout, woutT, 256, 256);
  rope_table<<<8, 256, 0, stream>>>(invf, ropecs);

  taa_fused<<<2048, 512, 0, stream>>>(x, wqkvT, woutT, bout, ropecs, out);
}

// Round 9
// 333.108 us; speedup vs baseline: 1.0097x; 1.0097x over previous
//
#include <hip/hip_runtime.h>
#include <hip/hip_bf16.h>

typedef __bf16 bf16_t;
typedef bf16_t bf16x4 __attribute__((ext_vector_type(4)));
typedef bf16_t bf16x8 __attribute__((ext_vector_type(8)));
typedef float f32x4 __attribute__((ext_vector_type(4)));
typedef unsigned int u32;

#define MFMA16(a, b, c) __builtin_amdgcn_mfma_f32_16x16x32_bf16((a), (b), (c), 0, 0, 0)

// element-index XOR swizzles (bf16 elems): XOR bits 3..5 keyed by row&7
__device__ __forceinline__ int sxi(int row, int e) { return row * 256 + (e ^ ((row & 7) << 3)); }
__device__ __forceinline__ int ski(int row, int e) { return row * 64 + (e ^ ((row & 7) << 3)); }

__device__ __forceinline__ u32 pk2(float a, float b) {
  union { bf16_t h[2]; u32 u; } x;
  x.h[0] = (bf16_t)a; x.h[1] = (bf16_t)b;
  return x.u;
}

// ---------------------------------------------------------------------------
// prep kernels
// ---------------------------------------------------------------------------
__global__ void transpose_to_bf16(const float* __restrict__ in, bf16_t* __restrict__ outp,
                                  int K, int N) {
  __shared__ float tile[32][33];
  const int k0 = blockIdx.x * 32;
  const int n0 = blockIdx.y * 32;
  const int tx = threadIdx.x;
  const int ty = threadIdx.y;
#pragma unroll
  for (int i = 0; i < 32; i += 8)
    tile[ty + i][tx] = in[(size_t)(k0 + ty + i) * N + (n0 + tx)];
  __syncthreads();
#pragma unroll
  for (int i = 0; i < 32; i += 8)
    outp[(size_t)(n0 + ty + i) * K + (k0 + tx)] = (bf16_t)tile[tx][ty + i];
}

__global__ void rope_table(const float* __restrict__ invf, float2* __restrict__ cs) {
  const int idx = blockIdx.x * 256 + threadIdx.x;  // 0..2047 = 64*32
  const int t = idx >> 5;
  const int i = idx & 31;
  const float f = (float)t * invf[i];
  cs[idx] = make_float2(cosf(f), sinf(f));
}

// ---------------------------------------------------------------------------
// fused temporal-axial attention
// grid: 2048 = (b, hh*32+ww); block: 512 threads = 8 waves.
// wave (h = wid>>1, hf = wid&1): head h, row-half hf.
// __launch_bounds__(512,2): empirical arch-VGPR cap = 256/arg = 128 — fits the
// ~100-reg demand with NO spill (R8's (512,4) capped at 64 and spilled), and
// 128 regs + 64KB LDS -> 2 blocks/CU = 16 waves/CU (~50% occupancy).
// ---------------------------------------------------------------------------
__global__ __launch_bounds__(512, 2) void taa_fused(
    const float* __restrict__ x, const bf16_t* __restrict__ wqkvT,
    const bf16_t* __restrict__ woutT, const float* __restrict__ bout,
    const float2* __restrict__ ropecs, float* __restrict__ out) {
  __shared__ __attribute__((aligned(16))) bf16_t sA[64 * 256];  // x -> V^T[h][d][s]
  __shared__ __attribute__((aligned(16))) bf16_t sB[64 * 256];  // K[h][s][dd] -> P[h][t][s] -> O[t][256]

  const int tid = threadIdx.x;
  const int wid = tid >> 6;   // 0..7
  const int h = wid >> 1;     // head
  const int hf = wid & 1;     // row-half
  const int l = tid & 63;
  const int l16 = l & 15;
  const int g = l >> 4;  // 0..3

  const int site = blockIdx.x;
  const int b = site >> 10;
  const int sp = site & 1023;

  const size_t TS = 1024 * 256;  // time stride in elements
  const float* xp = x + (size_t)((b * 64) * 1024 + sp) * 256;
  float* op = out + (size_t)((b * 64) * 1024 + sp) * 256;

  // ---- P1: x tile (64x256 f32) -> sA bf16 (swizzled) ----
#pragma unroll
  for (int it = 0; it < 8; ++it) {
    const int idx = tid + it * 512;
    const int t = idx >> 6;
    const int c = (idx & 63) * 4;
    const float4 v = *(const float4*)(xp + (size_t)t * TS + c);
    bf16x4 o4;
    o4[0] = (bf16_t)v.x; o4[1] = (bf16_t)v.y; o4[2] = (bf16_t)v.z; o4[3] = (bf16_t)v.w;
    *(bf16x4*)&sA[sxi(t, c)] = o4;
  }
  __syncthreads();  // B1

  // ---- P2a: Q^T = WqT @ x^T (rows dd 0..63, cols t = wave's half), rope -> qtb ----
  u32 qtb[4][2][2];
  {
    f32x4 qt[4][2] = {};
#pragma unroll
    for (int k0 = 0; k0 < 256; k0 += 32) {
      const int ko = k0 + 8 * g;
      bf16x8 aw[4], bx[2];
#pragma unroll
      for (int m = 0; m < 4; ++m)
        aw[m] = *(const bf16x8*)&wqkvT[(size_t)(h * 64 + 16 * m + l16) * 256 + ko];
#pragma unroll
      for (int n = 0; n < 2; ++n) bx[n] = *(const bf16x8*)&sA[sxi(hf * 32 + 16 * n + l16, ko)];
#pragma unroll
      for (int m = 0; m < 4; ++m)
#pragma unroll
        for (int n = 0; n < 2; ++n) qt[m][n] = MFMA16(aw[m], bx[n], qt[m][n]);
    }
    const float qs = 0.125f * 1.44269504088896f;
#pragma unroll
    for (int m = 0; m < 4; ++m)
#pragma unroll
      for (int n = 0; n < 2; ++n)
#pragma unroll
        for (int c = 0; c < 2; ++c) {
          const float v0 = qt[m][n][2 * c], v1 = qt[m][n][2 * c + 1];
          const int tg = hf * 32 + 16 * n + l16;
          const float2 cs = ropecs[tg * 32 + 8 * m + 2 * g + c];
          qtb[m][n][c] = pk2((v0 * cs.x - v1 * cs.y) * qs, (v1 * cs.x + v0 * cs.y) * qs);
        }
  }

  // ---- P2b: K = x @ Wk (rows s = wave's half), rope, -> sB immediately (ka dies) ----
  {
    f32x4 ka[2][4] = {};
#pragma unroll
    for (int k0 = 0; k0 < 256; k0 += 32) {
      const int ko = k0 + 8 * g;
      bf16x8 ax[2];
#pragma unroll
      for (int m = 0; m < 2; ++m) ax[m] = *(const bf16x8*)&sA[sxi(hf * 32 + 16 * m + l16, ko)];
#pragma unroll
      for (int n = 0; n < 4; ++n) {
        const bf16x8 bw = *(const bf16x8*)&wqkvT[(size_t)(256 + h * 64 + 16 * n + l16) * 256 + ko];
#pragma unroll
        for (int m = 0; m < 2; ++m) ka[m][n] = MFMA16(ax[m], bw, ka[m][n]);
      }
    }
#pragma unroll
    for (int m = 0; m < 2; ++m)
#pragma unroll
      for (int n = 0; n < 4; ++n)
#pragma unroll
        for (int r = 0; r < 4; ++r) {
          const float v = ka[m][n][r];
          const float p = __shfl_xor(v, 1);
          const int s = hf * 32 + 16 * m + 4 * g + r;
          const int dd = 16 * n + l16;
          const float2 cs = ropecs[s * 32 + 8 * n + (l16 >> 1)];
          const float o = (dd & 1) ? (v * cs.x + p * cs.y) : (v * cs.x - p * cs.y);
          sB[h * 4096 + ski(s, dd)] = (bf16_t)o;  // K region: no aliasing, write now
        }
  }

  // ---- P2c: V = x @ Wv (rows s = wave's half); va held until B2 ----
  f32x4 va[2][4] = {};
#pragma unroll
  for (int k0 = 0; k0 < 256; k0 += 32) {
    const int ko = k0 + 8 * g;
    bf16x8 ax[2];
#pragma unroll
    for (int m = 0; m < 2; ++m) ax[m] = *(const bf16x8*)&sA[sxi(hf * 32 + 16 * m + l16, ko)];
#pragma unroll
    for (int n = 0; n < 4; ++n) {
      const bf16x8 bw = *(const bf16x8*)&wqkvT[(size_t)(512 + h * 64 + 16 * n + l16) * 256 + ko];
#pragma unroll
      for (int m = 0; m < 2; ++m) va[m][n] = MFMA16(ax[m], bw, va[m][n]);
    }
  }
  __syncthreads();  // B2: x dead everywhere

  // V^T[h][d][s] into sA (transposed scatter)
#pragma unroll
  for (int m = 0; m < 2; ++m)
#pragma unroll
    for (int n = 0; n < 4; ++n)
#pragma unroll
      for (int r = 0; r < 4; ++r)
        sA[h * 4096 + ski(16 * n + l16, hf * 32 + 16 * m + 4 * g + r)] = (bf16_t)va[m][n][r];
  __syncthreads();  // B3: K, V^T visible

  // ---- 3a: S^T = K @ Q^T (A = K full 64 rows from sB; B = Q^T via pair-shfl) ----
  f32x4 sc[4][2] = {};
#pragma unroll
  for (int ks = 0; ks < 2; ++ks) {
    const int ko = ks * 32 + 8 * g;
    bf16x8 ak[4];
#pragma unroll
    for (int m = 0; m < 4; ++m) ak[m] = *(const bf16x8*)&sB[h * 4096 + ski(16 * m + l16, ko)];
#pragma unroll
    for (int n = 0; n < 2; ++n) {
      union { u32 u[4]; bf16x8 v; } uu;
#pragma unroll
      for (int k2 = 0; k2 < 4; ++k2) {
        const int src = ((((2 * g + (k2 >> 1)) & 3) << 4) | l16);
        const u32 a0 = (u32)__shfl((int)qtb[2 * ks][n][k2 & 1], src);
        const u32 a1 = (u32)__shfl((int)qtb[2 * ks + 1][n][k2 & 1], src);
        uu.u[k2] = (g & 2) ? a1 : a0;
      }
#pragma unroll
      for (int m = 0; m < 4; ++m) sc[m][n] = MFMA16(ak[m], uu.v, sc[m][n]);
    }
  }
  __syncthreads();  // B4: all K reads done -> P may overwrite

  // ---- 3b: causal softmax over s; P[t][s] -> sB (over K) ----
#pragma unroll
  for (int n = 0; n < 2; ++n) {
    const int t = hf * 32 + 16 * n + l16;
    float vals[16];
    float mx = -3.0e38f;
#pragma unroll
    for (int m = 0; m < 4; ++m)
#pragma unroll
      for (int r = 0; r < 4; ++r) {
        const int s = 16 * m + 4 * g + r;
        const float v = (s <= t) ? sc[m][n][r] : -3.0e38f;
        vals[4 * m + r] = v;
        mx = fmaxf(mx, v);
      }
    mx = fmaxf(mx, __shfl_xor(mx, 16));
    mx = fmaxf(mx, __shfl_xor(mx, 32));
    float sum = 0.f;
#pragma unroll
    for (int i = 0; i < 16; ++i) {
      vals[i] = exp2f(vals[i] - mx);
      sum += vals[i];
    }
    sum += __shfl_xor(sum, 16);
    sum += __shfl_xor(sum, 32);
    const float inv = 1.0f / sum;
#pragma unroll
    for (int m = 0; m < 4; ++m) {
      bf16x4 p4;
#pragma unroll
      for (int r = 0; r < 4; ++r) p4[r] = (bf16_t)(vals[4 * m + r] * inv);
      *(bf16x4*)&sB[h * 4096 + ski(t, 16 * m + 4 * g)] = p4;
    }
  }

  // ---- 3c: O = P @ V (A = own P rows; B = V^T rows d, b128) ----
  f32x4 oacc[2][4] = {};
#pragma unroll
  for (int ks = 0; ks < 2; ++ks) {
    const int ko = ks * 32 + 8 * g;
    bf16x8 ap[2], bv[4];
#pragma unroll
    for (int m = 0; m < 2; ++m)
      ap[m] = *(const bf16x8*)&sB[h * 4096 + ski(hf * 32 + 16 * m + l16, ko)];
#pragma unroll
    for (int n = 0; n < 4; ++n)
      bv[n] = *(const bf16x8*)&sA[h * 4096 + ski(16 * n + l16, ko)];
#pragma unroll
    for (int m = 0; m < 2; ++m)
#pragma unroll
      for (int n = 0; n < 4; ++n) oacc[m][n] = MFMA16(ap[m], bv[n], oacc[m][n]);
  }
  __syncthreads();  // B5: P/V dead -> O may overwrite sB

  // ---- P4: O -> sB[t][h*64+d] (full 64x256, sxi) ----
#pragma unroll
  for (int m = 0; m < 2; ++m)
#pragma unroll
    for (int n = 0; n < 4; ++n)
#pragma unroll
      for (int r = 0; r < 4; ++r)
        sB[sxi(hf * 32 + 16 * m + 4 * g + r, h * 64 + 16 * n + l16)] = (bf16_t)oacc[m][n][r];
  __syncthreads();  // B6

  // ---- P5: out = O @ w_out + b (wave -> 32 cols: wid*32..) ----
  f32x4 acc[4][2] = {};
#pragma unroll
  for (int k0 = 0; k0 < 256; k0 += 32) {
    const int ko = k0 + 8 * g;
    bf16x8 af[4];
#pragma unroll
    for (int m = 0; m < 4; ++m) af[m] = *(const bf16x8*)&sB[sxi(16 * m + l16, ko)];
#pragma unroll
    for (int n = 0; n < 2; ++n) {
      const bf16x8 bw = *(const bf16x8*)&woutT[(size_t)(wid * 32 + 16 * n + l16) * 256 + ko];
#pragma unroll
      for (int m = 0; m < 4; ++m) acc[m][n] = MFMA16(af[m], bw, acc[m][n]);
    }
  }
  float bb[2];
#pragma unroll
  for (int n = 0; n < 2; ++n) bb[n] = bout[wid * 32 + 16 * n + l16];
#pragma unroll
  for (int m = 0; m < 4; ++m)
#pragma unroll
    for (int n = 0; n < 2; ++n)
#pragma unroll
      for (int r = 0; r < 4; ++r) {
        const int t = 16 * m + 4 * g + r;
        const int col = wid * 32 + 16 * n + l16;
        op[(size_t)t * TS + col] = acc[m][n][r] + bb[n];
      }
}

// ---------------------------------------------------------------------------
extern "C" void kernel_launch(void* const* d_in, const int* in_sizes, int n_in,
                              void* d_out, int out_size, void* d_ws, size_t ws_size,
                              hipStream_t stream) {
  const float* x = (const float*)d_in[0];
  const float* wqkv = (const float*)d_in[1];
  const float* wout = (const float*)d_in[2];
  const float* bout = (const float*)d_in[3];
  const float* invf = (const float*)d_in[4];
  float* out = (float*)d_out;

  char* ws = (char*)d_ws;
  bf16_t* wqkvT = (bf16_t*)ws;                       // 768*256*2 = 393216 B
  bf16_t* woutT = (bf16_t*)(ws + 393216);            // 256*256*2 = 131072 B
  float2* ropecs = (float2*)(ws + 393216 + 131072);  // 2048*8 = 16384 B

  transpose_to_bf16<<<dim3(8, 24), dim3(32, 8), 0, stream>>>(wqkv, wqkvT, 256, 768);
  transpose_to_bf16<<<dim3(8, 8), dim3(32, 8), 0, stream>>>(wout, woutT, 256, 256);
  rope_table<<<8, 256, 0, stream>>>(invf, ropecs);

  taa_fused<<<2048, 512, 0, stream>>>(x, wqkvT, woutT, bout, ropecs, out);
}

// Round 10
// 321.958 us; speedup vs baseline: 1.0447x; 1.0346x over previous
//
#include <hip/hip_runtime.h>
#include <hip/hip_bf16.h>

typedef __bf16 bf16_t;
typedef bf16_t bf16x4 __attribute__((ext_vector_type(4)));
typedef bf16_t bf16x8 __attribute__((ext_vector_type(8)));
typedef float f32x4 __attribute__((ext_vector_type(4)));
typedef unsigned int u32;

#define MFMA16(a, b, c) __builtin_amdgcn_mfma_f32_16x16x32_bf16((a), (b), (c), 0, 0, 0)

// element-index XOR swizzles (bf16 elems): XOR bits 3..5 keyed by row&7
__device__ __forceinline__ int sxi(int row, int e) { return row * 256 + (e ^ ((row & 7) << 3)); }
__device__ __forceinline__ int ski(int row, int e) { return row * 64 + (e ^ ((row & 7) << 3)); }

__device__ __forceinline__ u32 pk2(float a, float b) {
  union { bf16_t h[2]; u32 u; } x;
  x.h[0] = (bf16_t)a; x.h[1] = (bf16_t)b;
  return x.u;
}

// ---------------------------------------------------------------------------
// prep kernels
// ---------------------------------------------------------------------------
__global__ void transpose_to_bf16(const float* __restrict__ in, bf16_t* __restrict__ outp,
                                  int K, int N) {
  __shared__ float tile[32][33];
  const int k0 = blockIdx.x * 32;
  const int n0 = blockIdx.y * 32;
  const int tx = threadIdx.x;
  const int ty = threadIdx.y;
#pragma unroll
  for (int i = 0; i < 32; i += 8)
    tile[ty + i][tx] = in[(size_t)(k0 + ty + i) * N + (n0 + tx)];
  __syncthreads();
#pragma unroll
  for (int i = 0; i < 32; i += 8)
    outp[(size_t)(n0 + ty + i) * K + (k0 + tx)] = (bf16_t)tile[tx][ty + i];
}

__global__ void rope_table(const float* __restrict__ invf, float2* __restrict__ cs) {
  const int idx = blockIdx.x * 256 + threadIdx.x;  // 0..2047 = 64*32
  const int t = idx >> 5;
  const int i = idx & 31;
  const float f = (float)t * invf[i];
  cs[idx] = make_float2(cosf(f), sinf(f));
}

// ---------------------------------------------------------------------------
// fused temporal-axial attention
// grid: 2048 = (b, hh*32+ww); block: 512 threads = 8 waves; wave=(head h, half hf).
// (512,4): total regs (VGPR+AGPR) capped at 128 -> 2 blocks/CU (16 waves).
// Demand reduced to ~96 by (a) P kept in registers via pair-shfl (no LDS, one
// fewer barrier), (b) V-GEMM after softmax so va never coexists with sc/vals.
// LDS: sA 32KB (x -> O), sB 32KB (K[h] -> V^T[h]).
// ---------------------------------------------------------------------------
__global__ __launch_bounds__(512, 4) void taa_fused(
    const float* __restrict__ x, const bf16_t* __restrict__ wqkvT,
    const bf16_t* __restrict__ woutT, const float* __restrict__ bout,
    const float2* __restrict__ ropecs, float* __restrict__ out) {
  __shared__ __attribute__((aligned(16))) bf16_t sA[64 * 256];   // x-tile -> O-tile
  __shared__ __attribute__((aligned(16))) bf16_t sB[4][64 * 64]; // K[h][s][dd] -> V^T[h][d][s]

  const int tid = threadIdx.x;
  const int wid = tid >> 6;   // 0..7
  const int h = wid >> 1;     // head
  const int hf = wid & 1;     // row-half
  const int l = tid & 63;
  const int l16 = l & 15;
  const int g = l >> 4;  // 0..3

  const int site = blockIdx.x;
  const int b = site >> 10;
  const int sp = site & 1023;

  const size_t TS = 1024 * 256;  // time stride in elements
  const float* xp = x + (size_t)((b * 64) * 1024 + sp) * 256;
  float* op = out + (size_t)((b * 64) * 1024 + sp) * 256;

  // ---- P1: x tile (64x256 f32) -> sA bf16 (swizzled) ----
#pragma unroll
  for (int it = 0; it < 8; ++it) {
    const int idx = tid + it * 512;
    const int t = idx >> 6;
    const int c = (idx & 63) * 4;
    const float4 v = *(const float4*)(xp + (size_t)t * TS + c);
    bf16x4 o4;
    o4[0] = (bf16_t)v.x; o4[1] = (bf16_t)v.y; o4[2] = (bf16_t)v.z; o4[3] = (bf16_t)v.w;
    *(bf16x4*)&sA[sxi(t, c)] = o4;
  }
  __syncthreads();  // B1

  // ---- P2a: Q^T = WqT @ x^T (rows dd 0..63, cols t = wave's half), rope -> qtb ----
  u32 qtb[4][2][2];
  {
    f32x4 qt[4][2] = {};
#pragma unroll
    for (int k0 = 0; k0 < 256; k0 += 32) {
      const int ko = k0 + 8 * g;
      bf16x8 aw[4], bx[2];
#pragma unroll
      for (int m = 0; m < 4; ++m)
        aw[m] = *(const bf16x8*)&wqkvT[(size_t)(h * 64 + 16 * m + l16) * 256 + ko];
#pragma unroll
      for (int n = 0; n < 2; ++n) bx[n] = *(const bf16x8*)&sA[sxi(hf * 32 + 16 * n + l16, ko)];
#pragma unroll
      for (int m = 0; m < 4; ++m)
#pragma unroll
        for (int n = 0; n < 2; ++n) qt[m][n] = MFMA16(aw[m], bx[n], qt[m][n]);
    }
    const float qs = 0.125f * 1.44269504088896f;
#pragma unroll
    for (int m = 0; m < 4; ++m)
#pragma unroll
      for (int n = 0; n < 2; ++n)
#pragma unroll
        for (int c = 0; c < 2; ++c) {
          const float v0 = qt[m][n][2 * c], v1 = qt[m][n][2 * c + 1];
          const int tg = hf * 32 + 16 * n + l16;
          const float2 cs = ropecs[tg * 32 + 8 * m + 2 * g + c];
          qtb[m][n][c] = pk2((v0 * cs.x - v1 * cs.y) * qs, (v1 * cs.x + v0 * cs.y) * qs);
        }
  }

  // ---- P2b: K = x @ Wk (rows s = wave's half), rope, -> sB[h] (ka dies here) ----
  {
    f32x4 ka[2][4] = {};
#pragma unroll
    for (int k0 = 0; k0 < 256; k0 += 32) {
      const int ko = k0 + 8 * g;
      bf16x8 ax[2];
#pragma unroll
      for (int m = 0; m < 2; ++m) ax[m] = *(const bf16x8*)&sA[sxi(hf * 32 + 16 * m + l16, ko)];
#pragma unroll
      for (int n = 0; n < 4; ++n) {
        const bf16x8 bw = *(const bf16x8*)&wqkvT[(size_t)(256 + h * 64 + 16 * n + l16) * 256 + ko];
#pragma unroll
        for (int m = 0; m < 2; ++m) ka[m][n] = MFMA16(ax[m], bw, ka[m][n]);
      }
    }
#pragma unroll
    for (int m = 0; m < 2; ++m)
#pragma unroll
      for (int n = 0; n < 4; ++n)
#pragma unroll
        for (int r = 0; r < 4; ++r) {
          const float v = ka[m][n][r];
          const float p = __shfl_xor(v, 1);
          const int s = hf * 32 + 16 * m + 4 * g + r;
          const int dd = 16 * n + l16;
          const float2 cs = ropecs[s * 32 + 8 * n + (l16 >> 1)];
          const float o = (dd & 1) ? (v * cs.x + p * cs.y) : (v * cs.x - p * cs.y);
          sB[h][ski(s, dd)] = (bf16_t)o;
        }
  }
  __syncthreads();  // B2: K visible to both head-waves

  // ---- 3a: S^T = K @ Q^T (A = K full 64 rows from sB[h]; B = Q^T via pair-shfl) ----
  f32x4 sc[4][2] = {};
#pragma unroll
  for (int ks = 0; ks < 2; ++ks) {
    const int ko = ks * 32 + 8 * g;
    bf16x8 ak[4];
#pragma unroll
    for (int m = 0; m < 4; ++m) ak[m] = *(const bf16x8*)&sB[h][ski(16 * m + l16, ko)];
#pragma unroll
    for (int n = 0; n < 2; ++n) {
      union { u32 u[4]; bf16x8 v; } uu;
#pragma unroll
      for (int k2 = 0; k2 < 4; ++k2) {
        const int src = ((((2 * g + (k2 >> 1)) & 3) << 4) | l16);
        const u32 a0 = (u32)__shfl((int)qtb[2 * ks][n][k2 & 1], src);
        const u32 a1 = (u32)__shfl((int)qtb[2 * ks + 1][n][k2 & 1], src);
        uu.u[k2] = (g & 2) ? a1 : a0;
      }
#pragma unroll
      for (int m = 0; m < 4; ++m) sc[m][n] = MFMA16(ak[m], uu.v, sc[m][n]);
    }
  }

  // ---- 3b: causal softmax over s; P packed to registers pb (no LDS) ----
  u32 pb[4][2][2];
#pragma unroll
  for (int n = 0; n < 2; ++n) {
    const int t = hf * 32 + 16 * n + l16;
    float vals[16];
    float mx = -3.0e38f;
#pragma unroll
    for (int m = 0; m < 4; ++m)
#pragma unroll
      for (int r = 0; r < 4; ++r) {
        const int s = 16 * m + 4 * g + r;
        const float v = (s <= t) ? sc[m][n][r] : -3.0e38f;
        vals[4 * m + r] = v;
        mx = fmaxf(mx, v);
      }
    mx = fmaxf(mx, __shfl_xor(mx, 16));
    mx = fmaxf(mx, __shfl_xor(mx, 32));
    float sum = 0.f;
#pragma unroll
    for (int i = 0; i < 16; ++i) {
      vals[i] = exp2f(vals[i] - mx);
      sum += vals[i];
    }
    sum += __shfl_xor(sum, 16);
    sum += __shfl_xor(sum, 32);
    const float inv = 1.0f / sum;
#pragma unroll
    for (int m = 0; m < 4; ++m)
#pragma unroll
      for (int c = 0; c < 2; ++c)
        pb[m][n][c] = pk2(vals[4 * m + 2 * c] * inv, vals[4 * m + 2 * c + 1] * inv);
  }

  // ---- 3c-v: V = x @ Wv (rows s = wave's half) — after softmax, sc/vals dead ----
  f32x4 va[2][4] = {};
#pragma unroll
  for (int k0 = 0; k0 < 256; k0 += 32) {
    const int ko = k0 + 8 * g;
    bf16x8 ax[2];
#pragma unroll
    for (int m = 0; m < 2; ++m) ax[m] = *(const bf16x8*)&sA[sxi(hf * 32 + 16 * m + l16, ko)];
#pragma unroll
    for (int n = 0; n < 4; ++n) {
      const bf16x8 bw = *(const bf16x8*)&wqkvT[(size_t)(512 + h * 64 + 16 * n + l16) * 256 + ko];
#pragma unroll
      for (int m = 0; m < 2; ++m) va[m][n] = MFMA16(ax[m], bw, va[m][n]);
    }
  }
  __syncthreads();  // B3: x reads done (sA free), K reads done (sB[h] free)

  // V^T[d][s] into sB[h] (over K)
#pragma unroll
  for (int m = 0; m < 2; ++m)
#pragma unroll
    for (int n = 0; n < 4; ++n)
#pragma unroll
      for (int r = 0; r < 4; ++r)
        sB[h][ski(16 * n + l16, hf * 32 + 16 * m + 4 * g + r)] = (bf16_t)va[m][n][r];
  __syncthreads();  // B4: V^T visible

  // ---- 3c: O = P @ V (A = P from pb via pair-shfl; B = V^T rows d, b128) ----
  f32x4 oacc[2][4] = {};
#pragma unroll
  for (int ks = 0; ks < 2; ++ks) {
    const int ko = ks * 32 + 8 * g;
    bf16x8 bv[4];
#pragma unroll
    for (int n = 0; n < 4; ++n) bv[n] = *(const bf16x8*)&sB[h][ski(16 * n + l16, ko)];
#pragma unroll
    for (int m = 0; m < 2; ++m) {
      union { u32 u[4]; bf16x8 v; } uu;
#pragma unroll
      for (int k2 = 0; k2 < 4; ++k2) {
        const int src = ((((2 * g + (k2 >> 1)) & 3) << 4) | l16);
        const u32 a0 = (u32)__shfl((int)pb[2 * ks][m][k2 & 1], src);
        const u32 a1 = (u32)__shfl((int)pb[2 * ks + 1][m][k2 & 1], src);
        uu.u[k2] = (g & 2) ? a1 : a0;
      }
#pragma unroll
      for (int n = 0; n < 4; ++n) oacc[m][n] = MFMA16(uu.v, bv[n], oacc[m][n]);
    }
  }

  // ---- P4: O -> sA[t][h*64+d] (x region, dead since B3) ----
#pragma unroll
  for (int m = 0; m < 2; ++m)
#pragma unroll
    for (int n = 0; n < 4; ++n)
#pragma unroll
      for (int r = 0; r < 4; ++r)
        sA[sxi(hf * 32 + 16 * m + 4 * g + r, h * 64 + 16 * n + l16)] = (bf16_t)oacc[m][n][r];
  __syncthreads();  // B5: O visible

  // ---- P5: out = O @ w_out + b (wave -> 32 cols: wid*32..) ----
  f32x4 acc[4][2] = {};
#pragma unroll
  for (int k0 = 0; k0 < 256; k0 += 32) {
    const int ko = k0 + 8 * g;
    bf16x8 af[4];
#pragma unroll
    for (int m = 0; m < 4; ++m) af[m] = *(const bf16x8*)&sA[sxi(16 * m + l16, ko)];
#pragma unroll
    for (int n = 0; n < 2; ++n) {
      const bf16x8 bw = *(const bf16x8*)&woutT[(size_t)(wid * 32 + 16 * n + l16) * 256 + ko];
#pragma unroll
      for (int m = 0; m < 4; ++m) acc[m][n] = MFMA16(af[m], bw, acc[m][n]);
    }
  }
  float bb[2];
#pragma unroll
  for (int n = 0; n < 2; ++n) bb[n] = bout[wid * 32 + 16 * n + l16];
#pragma unroll
  for (int m = 0; m < 4; ++m)
#pragma unroll
    for (int n = 0; n < 2; ++n)
#pragma unroll
      for (int r = 0; r < 4; ++r) {
        const int t = 16 * m + 4 * g + r;
        const int col = wid * 32 + 16 * n + l16;
        op[(size_t)t * TS + col] = acc[m][n][r] + bb[n];
      }
}

// ---------------------------------------------------------------------------
extern "C" void kernel_launch(void* const* d_in, const int* in_sizes, int n_in,
                              void* d_out, int out_size, void* d_ws, size_t ws_size,
                              hipStream_t stream) {
  const float* x = (const float*)d_in[0];
  const float* wqkv = (const float*)d_in[1];
  const float* wout = (const float*)d_in[2];
  const float* bout = (const float*)d_in[3];
  const float* invf = (const float*)d_in[4];
  float* out = (float*)d_out;

  char* ws = (char*)d_ws;
  bf16_t* wqkvT = (bf16_t*)ws;                       // 768*256*2 = 393216 B
  bf16_t* woutT = (bf16_t*)(ws + 393216);            // 256*256*2 = 131072 B
  float2* ropecs = (float2*)(ws + 393216 + 131072);  // 2048*8 = 16384 B

  transpose_to_bf16<<<dim3(8, 24), dim3(32, 8), 0, stream>>>(wqkv, wqkvT, 256, 768);
  transpose_to_bf16<<<dim3(8, 8), dim3(32, 8), 0, stream>>>(wout, woutT, 256, 256);
  rope_table<<<8, 256, 0, stream>>>(invf, ropecs);

  taa_fused<<<2048, 512, 0, stream>>>(x, wqkvT, woutT, bout, ropecs, out);
}

// Round 11
// 314.048 us; speedup vs baseline: 1.0710x; 1.0252x over previous
//
#include <hip/hip_runtime.h>
#include <hip/hip_bf16.h>

typedef __bf16 bf16_t;
typedef bf16_t bf16x4 __attribute__((ext_vector_type(4)));
typedef bf16_t bf16x8 __attribute__((ext_vector_type(8)));
typedef float f32x4 __attribute__((ext_vector_type(4)));
typedef unsigned int u32;

#define MFMA16(a, b, c) __builtin_amdgcn_mfma_f32_16x16x32_bf16((a), (b), (c), 0, 0, 0)

// element-index XOR swizzles (bf16 elems): XOR bits 3..5 keyed by row&7
__device__ __forceinline__ int sxi(int row, int e) { return row * 256 + (e ^ ((row & 7) << 3)); }
__device__ __forceinline__ int ski(int row, int e) { return row * 64 + (e ^ ((row & 7) << 3)); }

__device__ __forceinline__ u32 pk2(float a, float b) {
  union { bf16_t h[2]; u32 u; } x;
  x.h[0] = (bf16_t)a; x.h[1] = (bf16_t)b;
  return x.u;
}

// ---------------------------------------------------------------------------
// prep kernels
// ---------------------------------------------------------------------------
__global__ void transpose_to_bf16(const float* __restrict__ in, bf16_t* __restrict__ outp,
                                  int K, int N) {
  __shared__ float tile[32][33];
  const int k0 = blockIdx.x * 32;
  const int n0 = blockIdx.y * 32;
  const int tx = threadIdx.x;
  const int ty = threadIdx.y;
#pragma unroll
  for (int i = 0; i < 32; i += 8)
    tile[ty + i][tx] = in[(size_t)(k0 + ty + i) * N + (n0 + tx)];
  __syncthreads();
#pragma unroll
  for (int i = 0; i < 32; i += 8)
    outp[(size_t)(n0 + ty + i) * K + (k0 + tx)] = (bf16_t)tile[tx][ty + i];
}

__global__ void rope_table(const float* __restrict__ invf, float2* __restrict__ cs) {
  const int idx = blockIdx.x * 256 + threadIdx.x;  // 0..2047 = 64*32
  const int t = idx >> 5;
  const int i = idx & 31;
  const float f = (float)t * invf[i];
  cs[idx] = make_float2(cosf(f), sinf(f));
}

// ---------------------------------------------------------------------------
// fused temporal-axial attention
// grid: 2048 = (b, hh*32+ww); block: 512 threads = 8 waves; wave=(head h, half hf).
// (512,3): arch-VGPR cap = 256/3 = 85 (empirical cap model, 5 data points).
// Total regs ~85+32acc ~ 117 <= 128 -> 4 waves/SIMD = 2 blocks/CU, LDS 64KB.
// Demand cuts vs R10: softmax recomputes exp2 (no vals[16]); unroll-2 GEMM
// k-loops to stop the pipeliner from inflating register pressure.
// ---------------------------------------------------------------------------
__global__ __launch_bounds__(512, 3) void taa_fused(
    const float* __restrict__ x, const bf16_t* __restrict__ wqkvT,
    const bf16_t* __restrict__ woutT, const float* __restrict__ bout,
    const float2* __restrict__ ropecs, float* __restrict__ out) {
  __shared__ __attribute__((aligned(16))) bf16_t sA[64 * 256];   // x-tile -> O-tile
  __shared__ __attribute__((aligned(16))) bf16_t sB[4][64 * 64]; // K[h][s][dd] -> V^T[h][d][s]

  const int tid = threadIdx.x;
  const int wid = tid >> 6;   // 0..7
  const int h = wid >> 1;     // head
  const int hf = wid & 1;     // row-half
  const int l = tid & 63;
  const int l16 = l & 15;
  const int g = l >> 4;  // 0..3

  const int site = blockIdx.x;
  const int b = site >> 10;
  const int sp = site & 1023;

  const size_t TS = 1024 * 256;  // time stride in elements
  const float* xp = x + (size_t)((b * 64) * 1024 + sp) * 256;
  float* op = out + (size_t)((b * 64) * 1024 + sp) * 256;

  // ---- P1: x tile (64x256 f32) -> sA bf16 (swizzled) ----
#pragma unroll
  for (int it = 0; it < 8; ++it) {
    const int idx = tid + it * 512;
    const int t = idx >> 6;
    const int c = (idx & 63) * 4;
    const float4 v = *(const float4*)(xp + (size_t)t * TS + c);
    bf16x4 o4;
    o4[0] = (bf16_t)v.x; o4[1] = (bf16_t)v.y; o4[2] = (bf16_t)v.z; o4[3] = (bf16_t)v.w;
    *(bf16x4*)&sA[sxi(t, c)] = o4;
  }
  __syncthreads();  // B1

  // ---- P2a: Q^T = WqT @ x^T (rows dd 0..63, cols t = wave's half), rope -> qtb ----
  u32 qtb[4][2][2];
  {
    f32x4 qt[4][2] = {};
#pragma unroll 2
    for (int k0 = 0; k0 < 256; k0 += 32) {
      const int ko = k0 + 8 * g;
      bf16x8 aw[4], bx[2];
#pragma unroll
      for (int m = 0; m < 4; ++m)
        aw[m] = *(const bf16x8*)&wqkvT[(size_t)(h * 64 + 16 * m + l16) * 256 + ko];
#pragma unroll
      for (int n = 0; n < 2; ++n) bx[n] = *(const bf16x8*)&sA[sxi(hf * 32 + 16 * n + l16, ko)];
#pragma unroll
      for (int m = 0; m < 4; ++m)
#pragma unroll
        for (int n = 0; n < 2; ++n) qt[m][n] = MFMA16(aw[m], bx[n], qt[m][n]);
    }
    const float qs = 0.125f * 1.44269504088896f;
#pragma unroll
    for (int m = 0; m < 4; ++m)
#pragma unroll
      for (int n = 0; n < 2; ++n)
#pragma unroll
        for (int c = 0; c < 2; ++c) {
          const float v0 = qt[m][n][2 * c], v1 = qt[m][n][2 * c + 1];
          const int tg = hf * 32 + 16 * n + l16;
          const float2 cs = ropecs[tg * 32 + 8 * m + 2 * g + c];
          qtb[m][n][c] = pk2((v0 * cs.x - v1 * cs.y) * qs, (v1 * cs.x + v0 * cs.y) * qs);
        }
  }

  // ---- P2b: K = x @ Wk (rows s = wave's half), rope, -> sB[h] (ka dies here) ----
  {
    f32x4 ka[2][4] = {};
#pragma unroll 2
    for (int k0 = 0; k0 < 256; k0 += 32) {
      const int ko = k0 + 8 * g;
      bf16x8 ax[2];
#pragma unroll
      for (int m = 0; m < 2; ++m) ax[m] = *(const bf16x8*)&sA[sxi(hf * 32 + 16 * m + l16, ko)];
#pragma unroll
      for (int n = 0; n < 4; ++n) {
        const bf16x8 bw = *(const bf16x8*)&wqkvT[(size_t)(256 + h * 64 + 16 * n + l16) * 256 + ko];
#pragma unroll
        for (int m = 0; m < 2; ++m) ka[m][n] = MFMA16(ax[m], bw, ka[m][n]);
      }
    }
#pragma unroll
    for (int m = 0; m < 2; ++m)
#pragma unroll
      for (int n = 0; n < 4; ++n)
#pragma unroll
        for (int r = 0; r < 4; ++r) {
          const float v = ka[m][n][r];
          const float p = __shfl_xor(v, 1);
          const int s = hf * 32 + 16 * m + 4 * g + r;
          const int dd = 16 * n + l16;
          const float2 cs = ropecs[s * 32 + 8 * n + (l16 >> 1)];
          const float o = (dd & 1) ? (v * cs.x + p * cs.y) : (v * cs.x - p * cs.y);
          sB[h][ski(s, dd)] = (bf16_t)o;
        }
  }
  __syncthreads();  // B2: K visible to both head-waves

  // ---- 3a: S^T = K @ Q^T (A = K full 64 rows from sB[h]; B = Q^T via pair-shfl) ----
  f32x4 sc[4][2] = {};
#pragma unroll
  for (int ks = 0; ks < 2; ++ks) {
    const int ko = ks * 32 + 8 * g;
    bf16x8 ak[4];
#pragma unroll
    for (int m = 0; m < 4; ++m) ak[m] = *(const bf16x8*)&sB[h][ski(16 * m + l16, ko)];
#pragma unroll
    for (int n = 0; n < 2; ++n) {
      union { u32 u[4]; bf16x8 v; } uu;
#pragma unroll
      for (int k2 = 0; k2 < 4; ++k2) {
        const int src = ((((2 * g + (k2 >> 1)) & 3) << 4) | l16);
        const u32 a0 = (u32)__shfl((int)qtb[2 * ks][n][k2 & 1], src);
        const u32 a1 = (u32)__shfl((int)qtb[2 * ks + 1][n][k2 & 1], src);
        uu.u[k2] = (g & 2) ? a1 : a0;
      }
#pragma unroll
      for (int m = 0; m < 4; ++m) sc[m][n] = MFMA16(ak[m], uu.v, sc[m][n]);
    }
  }

  // ---- 3b: causal softmax over s; exp2 recomputed (no vals[] array) -> pb ----
  u32 pb[4][2][2];
#pragma unroll
  for (int n = 0; n < 2; ++n) {
    const int t = hf * 32 + 16 * n + l16;
    float mx = -3.0e38f;
#pragma unroll
    for (int m = 0; m < 4; ++m)
#pragma unroll
      for (int r = 0; r < 4; ++r) {
        const int s = 16 * m + 4 * g + r;
        mx = fmaxf(mx, (s <= t) ? sc[m][n][r] : -3.0e38f);
      }
    mx = fmaxf(mx, __shfl_xor(mx, 16));
    mx = fmaxf(mx, __shfl_xor(mx, 32));
    float sum = 0.f;
#pragma unroll
    for (int m = 0; m < 4; ++m)
#pragma unroll
      for (int r = 0; r < 4; ++r) {
        const int s = 16 * m + 4 * g + r;
        sum += exp2f(((s <= t) ? sc[m][n][r] : -3.0e38f) - mx);
      }
    sum += __shfl_xor(sum, 16);
    sum += __shfl_xor(sum, 32);
    const float inv = 1.0f / sum;
#pragma unroll
    for (int m = 0; m < 4; ++m)
#pragma unroll
      for (int c = 0; c < 2; ++c) {
        const int s0 = 16 * m + 4 * g + 2 * c;
        const float e0 = exp2f(((s0 <= t) ? sc[m][n][2 * c] : -3.0e38f) - mx) * inv;
        const float e1 = exp2f(((s0 + 1 <= t) ? sc[m][n][2 * c + 1] : -3.0e38f) - mx) * inv;
        pb[m][n][c] = pk2(e0, e1);
      }
  }

  // ---- 3c-v: V = x @ Wv (rows s = wave's half) — after softmax, sc dead ----
  f32x4 va[2][4] = {};
#pragma unroll 2
  for (int k0 = 0; k0 < 256; k0 += 32) {
    const int ko = k0 + 8 * g;
    bf16x8 ax[2];
#pragma unroll
    for (int m = 0; m < 2; ++m) ax[m] = *(const bf16x8*)&sA[sxi(hf * 32 + 16 * m + l16, ko)];
#pragma unroll
    for (int n = 0; n < 4; ++n) {
      const bf16x8 bw = *(const bf16x8*)&wqkvT[(size_t)(512 + h * 64 + 16 * n + l16) * 256 + ko];
#pragma unroll
      for (int m = 0; m < 2; ++m) va[m][n] = MFMA16(ax[m], bw, va[m][n]);
    }
  }
  __syncthreads();  // B3: x reads done (sA free), K reads done (sB[h] free)

  // V^T[d][s] into sB[h] (over K)
#pragma unroll
  for (int m = 0; m < 2; ++m)
#pragma unroll
    for (int n = 0; n < 4; ++n)
#pragma unroll
      for (int r = 0; r < 4; ++r)
        sB[h][ski(16 * n + l16, hf * 32 + 16 * m + 4 * g + r)] = (bf16_t)va[m][n][r];
  __syncthreads();  // B4: V^T visible

  // ---- 3c: O = P @ V (A = P from pb via pair-shfl; B = V^T rows d, b128) ----
  f32x4 oacc[2][4] = {};
#pragma unroll
  for (int ks = 0; ks < 2; ++ks) {
    const int ko = ks * 32 + 8 * g;
    bf16x8 bv[4];
#pragma unroll
    for (int n = 0; n < 4; ++n) bv[n] = *(const bf16x8*)&sB[h][ski(16 * n + l16, ko)];
#pragma unroll
    for (int m = 0; m < 2; ++m) {
      union { u32 u[4]; bf16x8 v; } uu;
#pragma unroll
      for (int k2 = 0; k2 < 4; ++k2) {
        const int src = ((((2 * g + (k2 >> 1)) & 3) << 4) | l16);
        const u32 a0 = (u32)__shfl((int)pb[2 * ks][m][k2 & 1], src);
        const u32 a1 = (u32)__shfl((int)pb[2 * ks + 1][m][k2 & 1], src);
        uu.u[k2] = (g & 2) ? a1 : a0;
      }
#pragma unroll
      for (int n = 0; n < 4; ++n) oacc[m][n] = MFMA16(uu.v, bv[n], oacc[m][n]);
    }
  }

  // ---- P4: O -> sA[t][h*64+d] (x region, dead since B3) ----
#pragma unroll
  for (int m = 0; m < 2; ++m)
#pragma unroll
    for (int n = 0; n < 4; ++n)
#pragma unroll
      for (int r = 0; r < 4; ++r)
        sA[sxi(hf * 32 + 16 * m + 4 * g + r, h * 64 + 16 * n + l16)] = (bf16_t)oacc[m][n][r];
  __syncthreads();  // B5: O visible

  // ---- P5: out = O @ w_out + b (wave -> 32 cols: wid*32..) ----
  f32x4 acc[4][2] = {};
#pragma unroll 2
  for (int k0 = 0; k0 < 256; k0 += 32) {
    const int ko = k0 + 8 * g;
    bf16x8 af[4];
#pragma unroll
    for (int m = 0; m < 4; ++m) af[m] = *(const bf16x8*)&sA[sxi(16 * m + l16, ko)];
#pragma unroll
    for (int n = 0; n < 2; ++n) {
      const bf16x8 bw = *(const bf16x8*)&woutT[(size_t)(wid * 32 + 16 * n + l16) * 256 + ko];
#pragma unroll
      for (int m = 0; m < 4; ++m) acc[m][n] = MFMA16(af[m], bw, acc[m][n]);
    }
  }
  float bb[2];
#pragma unroll
  for (int n = 0; n < 2; ++n) bb[n] = bout[wid * 32 + 16 * n + l16];
#pragma unroll
  for (int m = 0; m < 4; ++m)
#pragma unroll
    for (int n = 0; n < 2; ++n)
#pragma unroll
      for (int r = 0; r < 4; ++r) {
        const int t = 16 * m + 4 * g + r;
        const int col = wid * 32 + 16 * n + l16;
        op[(size_t)t * TS + col] = acc[m][n][r] + bb[n];
      }
}

// ---------------------------------------------------------------------------
extern "C" void kernel_launch(void* const* d_in, const int* in_sizes, int n_in,
                              void* d_out, int out_size, void* d_ws, size_t ws_size,
                              hipStream_t stream) {
  const float* x = (const float*)d_in[0];
  const float* wqkv = (const float*)d_in[1];
  const float* wout = (const float*)d_in[2];
  const float* bout = (const float*)d_in[3];
  const float* invf = (const float*)d_in[4];
  float* out = (float*)d_out;

  char* ws = (char*)d_ws;
  bf16_t* wqkvT = (bf16_t*)ws;                       // 768*256*2 = 393216 B
  bf16_t* woutT = (bf16_t*)(ws + 393216);            // 256*256*2 = 131072 B
  float2* ropecs = (float2*)(ws + 393216 + 131072);  // 2048*8 = 16384 B

  transpose_to_bf16<<<dim3(8, 24), dim3(32, 8), 0, stream>>>(wqkv, wqkvT, 256, 768);
  transpose_to_bf16<<<dim3(8, 8), dim3(32, 8), 0, stream>>>(wout, woutT, 256, 256);
  rope_table<<<8, 256, 0, stream>>>(invf, ropecs);

  taa_fused<<<2048, 512, 0, stream>>>(x, wqkvT, woutT, bout, ropecs, out);
}

// Round 12
// 289.725 us; speedup vs baseline: 1.1609x; 1.0839x over previous
//
#include <hip/hip_runtime.h>
#include <hip/hip_bf16.h>

typedef __bf16 bf16_t;
typedef bf16_t bf16x4 __attribute__((ext_vector_type(4)));
typedef bf16_t bf16x8 __attribute__((ext_vector_type(8)));
typedef float f32x4 __attribute__((ext_vector_type(4)));
typedef unsigned int u32;

#define MFMA16(a, b, c) __builtin_amdgcn_mfma_f32_16x16x32_bf16((a), (b), (c), 0, 0, 0)

// element-index XOR swizzles (bf16 elems): XOR bits 3..5 keyed by row&7
__device__ __forceinline__ int sxi(int row, int e) { return row * 256 + (e ^ ((row & 7) << 3)); }
__device__ __forceinline__ int ski(int row, int e) { return row * 64 + (e ^ ((row & 7) << 3)); }

__device__ __forceinline__ u32 pk2(float a, float b) {
  union { bf16_t h[2]; u32 u; } x;
  x.h[0] = (bf16_t)a; x.h[1] = (bf16_t)b;
  return x.u;
}

// ---------------------------------------------------------------------------
// prep kernels
// ---------------------------------------------------------------------------
__global__ void transpose_to_bf16(const float* __restrict__ in, bf16_t* __restrict__ outp,
                                  int K, int N) {
  __shared__ float tile[32][33];
  const int k0 = blockIdx.x * 32;
  const int n0 = blockIdx.y * 32;
  const int tx = threadIdx.x;
  const int ty = threadIdx.y;
#pragma unroll
  for (int i = 0; i < 32; i += 8)
    tile[ty + i][tx] = in[(size_t)(k0 + ty + i) * N + (n0 + tx)];
  __syncthreads();
#pragma unroll
  for (int i = 0; i < 32; i += 8)
    outp[(size_t)(n0 + ty + i) * K + (k0 + tx)] = (bf16_t)tile[tx][ty + i];
}

__global__ void rope_table(const float* __restrict__ invf, float2* __restrict__ cs) {
  const int idx = blockIdx.x * 256 + threadIdx.x;  // 0..2047 = 64*32
  const int t = idx >> 5;
  const int i = idx & 31;
  const float f = (float)t * invf[i];
  cs[idx] = make_float2(cosf(f), sinf(f));
}

// ---------------------------------------------------------------------------
// fused temporal-axial attention
// grid: 2048 = (b, hh*32+ww); block: 512 threads = 8 waves; wave=(head h, half hf).
// (512,4): total (VGPR+AGPR) cap 128 -> 4 waves/SIMD, 2 blocks/CU.
// Occupancy model (8 rounds of evidence): waves/SIMD = 512 / roundup(total,
// {64,128,256,512}). To fit 128: acc peak must be 32 -> GEMMs ordered K, Q, V
// so no two MFMA accumulators are ever live together; arch demand ~80 (R11).
// LDS: sA 32KB (x-tile -> V^T[h]) + sB 32KB (K[h] -> O-tile) = 64KB.
// ---------------------------------------------------------------------------
__global__ __launch_bounds__(512, 4) void taa_fused(
    const float* __restrict__ x, const bf16_t* __restrict__ wqkvT,
    const bf16_t* __restrict__ woutT, const float* __restrict__ bout,
    const float2* __restrict__ ropecs, float* __restrict__ out) {
  __shared__ __attribute__((aligned(16))) bf16_t sA[64 * 256];   // x-tile -> V^T[h][d][s]
  __shared__ __attribute__((aligned(16))) bf16_t sB[4][64 * 64]; // K[h][s][dd] -> O-tile[64][256]

  const int tid = threadIdx.x;
  const int wid = tid >> 6;   // 0..7
  const int h = wid >> 1;     // head
  const int hf = wid & 1;     // row-half
  const int l = tid & 63;
  const int l16 = l & 15;
  const int g = l >> 4;  // 0..3

  const int site = blockIdx.x;
  const int b = site >> 10;
  const int sp = site & 1023;

  const size_t TS = 1024 * 256;  // time stride in elements
  const float* xp = x + (size_t)((b * 64) * 1024 + sp) * 256;
  float* op = out + (size_t)((b * 64) * 1024 + sp) * 256;

  // ---- P1: x tile (64x256 f32) -> sA bf16 (swizzled) ----
#pragma unroll
  for (int it = 0; it < 8; ++it) {
    const int idx = tid + it * 512;
    const int t = idx >> 6;
    const int c = (idx & 63) * 4;
    const float4 v = *(const float4*)(xp + (size_t)t * TS + c);
    bf16x4 o4;
    o4[0] = (bf16_t)v.x; o4[1] = (bf16_t)v.y; o4[2] = (bf16_t)v.z; o4[3] = (bf16_t)v.w;
    *(bf16x4*)&sA[sxi(t, c)] = o4;
  }
  __syncthreads();  // B1

  // ---- P2-K: K = x @ Wk (rows s = wave's half), rope, -> sB[h] (ka dies) ----
  {
    f32x4 ka[2][4] = {};
#pragma unroll 2
    for (int k0 = 0; k0 < 256; k0 += 32) {
      const int ko = k0 + 8 * g;
      bf16x8 ax[2];
#pragma unroll
      for (int m = 0; m < 2; ++m) ax[m] = *(const bf16x8*)&sA[sxi(hf * 32 + 16 * m + l16, ko)];
#pragma unroll
      for (int n = 0; n < 4; ++n) {
        const bf16x8 bw = *(const bf16x8*)&wqkvT[(size_t)(256 + h * 64 + 16 * n + l16) * 256 + ko];
#pragma unroll
        for (int m = 0; m < 2; ++m) ka[m][n] = MFMA16(ax[m], bw, ka[m][n]);
      }
    }
#pragma unroll
    for (int m = 0; m < 2; ++m)
#pragma unroll
      for (int n = 0; n < 4; ++n)
#pragma unroll
        for (int r = 0; r < 4; ++r) {
          const float v = ka[m][n][r];
          const float p = __shfl_xor(v, 1);
          const int s = hf * 32 + 16 * m + 4 * g + r;
          const int dd = 16 * n + l16;
          const float2 cs = ropecs[s * 32 + 8 * n + (l16 >> 1)];
          const float o = (dd & 1) ? (v * cs.x + p * cs.y) : (v * cs.x - p * cs.y);
          sB[h][ski(s, dd)] = (bf16_t)o;
        }
  }

  // ---- P2-Q: Q^T = WqT @ x^T (rows dd, cols t = wave's half), rope -> qtb (qt dies) ----
  u32 qtb[4][2][2];
  {
    f32x4 qt[4][2] = {};
#pragma unroll 2
    for (int k0 = 0; k0 < 256; k0 += 32) {
      const int ko = k0 + 8 * g;
      bf16x8 aw[4], bx[2];
#pragma unroll
      for (int m = 0; m < 4; ++m)
        aw[m] = *(const bf16x8*)&wqkvT[(size_t)(h * 64 + 16 * m + l16) * 256 + ko];
#pragma unroll
      for (int n = 0; n < 2; ++n) bx[n] = *(const bf16x8*)&sA[sxi(hf * 32 + 16 * n + l16, ko)];
#pragma unroll
      for (int m = 0; m < 4; ++m)
#pragma unroll
        for (int n = 0; n < 2; ++n) qt[m][n] = MFMA16(aw[m], bx[n], qt[m][n]);
    }
    const float qs = 0.125f * 1.44269504088896f;
#pragma unroll
    for (int m = 0; m < 4; ++m)
#pragma unroll
      for (int n = 0; n < 2; ++n)
#pragma unroll
        for (int c = 0; c < 2; ++c) {
          const float v0 = qt[m][n][2 * c], v1 = qt[m][n][2 * c + 1];
          const int tg = hf * 32 + 16 * n + l16;
          const float2 cs = ropecs[tg * 32 + 8 * m + 2 * g + c];
          qtb[m][n][c] = pk2((v0 * cs.x - v1 * cs.y) * qs, (v1 * cs.x + v0 * cs.y) * qs);
        }
  }

  // ---- P2-V: V = x @ Wv (rows s = wave's half); va live only across B2 ----
  f32x4 va[2][4] = {};
#pragma unroll 2
  for (int k0 = 0; k0 < 256; k0 += 32) {
    const int ko = k0 + 8 * g;
    bf16x8 ax[2];
#pragma unroll
    for (int m = 0; m < 2; ++m) ax[m] = *(const bf16x8*)&sA[sxi(hf * 32 + 16 * m + l16, ko)];
#pragma unroll
    for (int n = 0; n < 4; ++n) {
      const bf16x8 bw = *(const bf16x8*)&wqkvT[(size_t)(512 + h * 64 + 16 * n + l16) * 256 + ko];
#pragma unroll
      for (int m = 0; m < 2; ++m) va[m][n] = MFMA16(ax[m], bw, va[m][n]);
    }
  }
  __syncthreads();  // B2: x dead everywhere, K visible

  // V^T[d][s] into sA slice of head h (over x region); va dies
#pragma unroll
  for (int m = 0; m < 2; ++m)
#pragma unroll
    for (int n = 0; n < 4; ++n)
#pragma unroll
      for (int r = 0; r < 4; ++r)
        sA[h * 4096 + ski(16 * n + l16, hf * 32 + 16 * m + 4 * g + r)] = (bf16_t)va[m][n][r];

  // ---- 3a: S^T = K @ Q^T (A = K full 64 rows from sB[h]; B = Q^T via pair-shfl) ----
  f32x4 sc[4][2] = {};
#pragma unroll
  for (int ks = 0; ks < 2; ++ks) {
    const int ko = ks * 32 + 8 * g;
    bf16x8 ak[4];
#pragma unroll
    for (int m = 0; m < 4; ++m) ak[m] = *(const bf16x8*)&sB[h][ski(16 * m + l16, ko)];
#pragma unroll
    for (int n = 0; n < 2; ++n) {
      union { u32 u[4]; bf16x8 v; } uu;
#pragma unroll
      for (int k2 = 0; k2 < 4; ++k2) {
        const int src = ((((2 * g + (k2 >> 1)) & 3) << 4) | l16);
        const u32 a0 = (u32)__shfl((int)qtb[2 * ks][n][k2 & 1], src);
        const u32 a1 = (u32)__shfl((int)qtb[2 * ks + 1][n][k2 & 1], src);
        uu.u[k2] = (g & 2) ? a1 : a0;
      }
#pragma unroll
      for (int m = 0; m < 4; ++m) sc[m][n] = MFMA16(ak[m], uu.v, sc[m][n]);
    }
  }

  // ---- 3b: causal softmax over s; exp2 recomputed; P packed -> pb; sc dies ----
  u32 pb[4][2][2];
#pragma unroll
  for (int n = 0; n < 2; ++n) {
    const int t = hf * 32 + 16 * n + l16;
    float mx = -3.0e38f;
#pragma unroll
    for (int m = 0; m < 4; ++m)
#pragma unroll
      for (int r = 0; r < 4; ++r) {
        const int s = 16 * m + 4 * g + r;
        mx = fmaxf(mx, (s <= t) ? sc[m][n][r] : -3.0e38f);
      }
    mx = fmaxf(mx, __shfl_xor(mx, 16));
    mx = fmaxf(mx, __shfl_xor(mx, 32));
    float sum = 0.f;
#pragma unroll
    for (int m = 0; m < 4; ++m)
#pragma unroll
      for (int r = 0; r < 4; ++r) {
        const int s = 16 * m + 4 * g + r;
        sum += exp2f(((s <= t) ? sc[m][n][r] : -3.0e38f) - mx);
      }
    sum += __shfl_xor(sum, 16);
    sum += __shfl_xor(sum, 32);
    const float inv = 1.0f / sum;
#pragma unroll
    for (int m = 0; m < 4; ++m)
#pragma unroll
      for (int c = 0; c < 2; ++c) {
        const int s0 = 16 * m + 4 * g + 2 * c;
        const float e0 = exp2f(((s0 <= t) ? sc[m][n][2 * c] : -3.0e38f) - mx) * inv;
        const float e1 = exp2f(((s0 + 1 <= t) ? sc[m][n][2 * c + 1] : -3.0e38f) - mx) * inv;
        pb[m][n][c] = pk2(e0, e1);
      }
  }
  __syncthreads();  // B3: V^T fully written by both halves; all K reads done

  // ---- 3c: O = P @ V (A = P from pb via pair-shfl; B = V^T rows d from sA, b128) ----
  f32x4 oacc[2][4] = {};
#pragma unroll
  for (int ks = 0; ks < 2; ++ks) {
    const int ko = ks * 32 + 8 * g;
    bf16x8 bv[4];
#pragma unroll
    for (int n = 0; n < 4; ++n) bv[n] = *(const bf16x8*)&sA[h * 4096 + ski(16 * n + l16, ko)];
#pragma unroll
    for (int m = 0; m < 2; ++m) {
      union { u32 u[4]; bf16x8 v; } uu;
#pragma unroll
      for (int k2 = 0; k2 < 4; ++k2) {
        const int src = ((((2 * g + (k2 >> 1)) & 3) << 4) | l16);
        const u32 a0 = (u32)__shfl((int)pb[2 * ks][m][k2 & 1], src);
        const u32 a1 = (u32)__shfl((int)pb[2 * ks + 1][m][k2 & 1], src);
        uu.u[k2] = (g & 2) ? a1 : a0;
      }
#pragma unroll
      for (int n = 0; n < 4; ++n) oacc[m][n] = MFMA16(uu.v, bv[n], oacc[m][n]);
    }
  }
  __syncthreads();  // B4: all V^T/K reads done -> sB reusable as O-tile

  // ---- P4: O -> sB viewed as [64][256] (swizzled); oacc dies ----
  {
    bf16_t* sBf = &sB[0][0];
#pragma unroll
    for (int m = 0; m < 2; ++m)
#pragma unroll
      for (int n = 0; n < 4; ++n)
#pragma unroll
        for (int r = 0; r < 4; ++r)
          sBf[sxi(hf * 32 + 16 * m + 4 * g + r, h * 64 + 16 * n + l16)] = (bf16_t)oacc[m][n][r];
  }
  __syncthreads();  // B5: O visible

  // ---- P5: out = O @ w_out + b (wave -> 32 cols: wid*32..) ----
  {
    const bf16_t* sBf = &sB[0][0];
    f32x4 acc[4][2] = {};
#pragma unroll 2
    for (int k0 = 0; k0 < 256; k0 += 32) {
      const int ko = k0 + 8 * g;
      bf16x8 af[4];
#pragma unroll
      for (int m = 0; m < 4; ++m) af[m] = *(const bf16x8*)&sBf[sxi(16 * m + l16, ko)];
#pragma unroll
      for (int n = 0; n < 2; ++n) {
        const bf16x8 bw = *(const bf16x8*)&woutT[(size_t)(wid * 32 + 16 * n + l16) * 256 + ko];
#pragma unroll
        for (int m = 0; m < 4; ++m) acc[m][n] = MFMA16(af[m], bw, acc[m][n]);
      }
    }
    float bb[2];
#pragma unroll
    for (int n = 0; n < 2; ++n) bb[n] = bout[wid * 32 + 16 * n + l16];
#pragma unroll
    for (int m = 0; m < 4; ++m)
#pragma unroll
      for (int n = 0; n < 2; ++n)
#pragma unroll
        for (int r = 0; r < 4; ++r) {
          const int t = 16 * m + 4 * g + r;
          const int col = wid * 32 + 16 * n + l16;
          op[(size_t)t * TS + col] = acc[m][n][r] + bb[n];
        }
  }
}

// ---------------------------------------------------------------------------
extern "C" void kernel_launch(void* const* d_in, const int* in_sizes, int n_in,
                              void* d_out, int out_size, void* d_ws, size_t ws_size,
                              hipStream_t stream) {
  const float* x = (const float*)d_in[0];
  const float* wqkv = (const float*)d_in[1];
  const float* wout = (const float*)d_in[2];
  const float* bout = (const float*)d_in[3];
  const float* invf = (const float*)d_in[4];
  float* out = (float*)d_out;

  char* ws = (char*)d_ws;
  bf16_t* wqkvT = (bf16_t*)ws;                       // 768*256*2 = 393216 B
  bf16_t* woutT = (bf16_t*)(ws + 393216);            // 256*256*2 = 131072 B
  float2* ropecs = (float2*)(ws + 393216 + 131072);  // 2048*8 = 16384 B

  transpose_to_bf16<<<dim3(8, 24), dim3(32, 8), 0, stream>>>(wqkv, wqkvT, 256, 768);
  transpose_to_bf16<<<dim3(8, 8), dim3(32, 8), 0, stream>>>(wout, woutT, 256, 256);
  rope_table<<<8, 256, 0, stream>>>(invf, ropecs);

  taa_fused<<<2048, 512, 0, stream>>>(x, wqkvT, woutT, bout, ropecs, out);
}